// Round 1
// baseline (790.721 us; speedup 1.0000x reference)
//
#include <hip/hip_runtime.h>

typedef unsigned int u32;
typedef unsigned long long u64;

// ---------------- workspace layout (floats) ----------------
// rel   : [0, 1572864)              (8*4096*16*3)
// pts4  : [1572864, 1703936)        (8*4096 float4: x,y,z,|p|^2)
// acc   : [1703936, +144)           mom[16] | gsum[64] | gsq[64]   (zeroed)
// s1/t1/s2/t2 : 64 each from 1704080
#define REL_OFF   0
#define PTS4_OFF  1572864
#define ACC_OFF   1703936

__global__ __launch_bounds__(256) void prep_kernel(const float* __restrict__ xyz,
                                                   float4* __restrict__ pts4){
#pragma clang fp contract(off)
  int g = blockIdx.x*256 + threadIdx.x;
  int b = g >> 12, n = g & 4095;
  const float* xb = xyz + (size_t)b*12288;
  float x = xb[n], y = xb[4096+n], z = xb[8192+n];
  float sq = (x*x + y*y) + z*z;
  pts4[g] = make_float4(x,y,z,sq);
}

// One block = 64 queries of one batch; wave w scans candidate quarter [w*1024, w*1024+1024).
// Per-lane top-17 via gated LDS append + wave-synchronized register compare-swap chain.
// Key = (monotone(f32 dist) << 32) | (4095 - j)  -> descending value, ties to lower index (jax top_k order).
__global__ __launch_bounds__(256) void knn_kernel(const float4* __restrict__ pts4,
                                                  float* __restrict__ rel,
                                                  float* __restrict__ mom){
#pragma clang fp contract(off)
  __shared__ u32 lA[4352];   // phase1: [tid*17+i] = mapped bits ; phase2: [(w*17+i)*64+L] = key hi
  __shared__ u32 lB[4352];   // phase1: j ; phase2: key lo
  const int tid  = threadIdx.x;
  const int lane = tid & 63;
  const int wave = tid >> 6;
  const int blk  = blockIdx.x;         // 512 = 8 batches * 64
  const int b    = blk >> 6;
  const int q0   = (blk & 63) << 6;
  const float4* __restrict__ P = pts4 + ((size_t)b << 12);
  const float4 me = P[q0 + lane];

  u64 s[17];
  #pragma unroll
  for (int i=0;i<17;i++) s[i] = 0ull;
  u32 kminhi = 0u;
  int cnt = 0;
  const int base = tid*17;
  const int j0 = __builtin_amdgcn_readfirstlane(wave << 10);

  for (int g8 = 0; g8 < 1024; g8 += 8){
    float4 c[8];
    #pragma unroll
    for (int u=0;u<8;u++) c[u] = P[j0 + g8 + u];   // wave-uniform address -> s_load
    #pragma unroll
    for (int u=0;u<8;u++){
      const int j = j0 + g8 + u;
      float dot = (me.x*c[u].x + me.y*c[u].y) + me.z*c[u].z;
      float d   = (me.w + c[u].w) - 2.0f*dot;
      u32 ub = __float_as_uint(d);
      ub ^= ((u32)(((int)ub) >> 31) | 0x80000000u);   // order-preserving map
      if (ub >= kminhi){                               // conservative gate (>= keeps ties)
        lA[base+cnt] = ub;
        lB[base+cnt] = (u32)j;
        cnt++;
      }
    }
    if (__any(cnt >= 9)){            // wave-uniform compaction; cnt <= 8+8 <= 16 < 17 always
      const int n_ = cnt; cnt = 0;
      for (int i=0;i<n_;i++){
        u64 key = ((u64)lA[base+i] << 32) | (u32)(4095 - (int)lB[base+i]);
        #pragma unroll
        for (int t=0;t<17;t++){
          bool gt = key > s[t];
          u64 mx = gt ? key : s[t];
          key = gt ? s[t] : key;
          s[t] = mx;
        }
      }
      kminhi = (u32)(s[16] >> 32);
    }
  }
  { // final flush
    const int n_ = cnt;
    for (int i=0;i<n_;i++){
      u64 key = ((u64)lA[base+i] << 32) | (u32)(4095 - (int)lB[base+i]);
      #pragma unroll
      for (int t=0;t<17;t++){
        bool gt = key > s[t];
        u64 mx = gt ? key : s[t];
        key = gt ? s[t] : key;
        s[t] = mx;
      }
    }
  }
  __syncthreads();                    // buffers dead; reuse LDS for sorted lists
  #pragma unroll
  for (int i=0;i<17;i++){
    const int o = ((wave*17 + i) << 6) + lane;
    lA[o] = (u32)(s[i] >> 32);
    lB[o] = (u32)s[i];
  }
  __syncthreads();

  // merge the 4 per-quarter sorted lists; wave w handles queries [w*16, w*16+16)
  float sm0=0,sm1=0,sm2=0,sm3=0,sm4=0,sm5=0,sm6=0,sm7=0,sm8=0;
  if (lane < 16){
    const int ql = (wave << 4) + lane;
    const float4 qp = P[q0 + ql];
    float* __restrict__ ro = rel + (size_t)((b << 12) + q0 + ql) * 48;
    int p0=0,p1=0,p2=0,p3=0;
    for (int r=0;r<17;r++){
      u64 k0 = ((u64)lA[(( 0+p0)<<6)+ql] << 32) | lB[(( 0+p0)<<6)+ql];
      u64 k1 = ((u64)lA[((17+p1)<<6)+ql] << 32) | lB[((17+p1)<<6)+ql];
      u64 k2 = ((u64)lA[((34+p2)<<6)+ql] << 32) | lB[((34+p2)<<6)+ql];
      u64 k3 = ((u64)lA[((51+p3)<<6)+ql] << 32) | lB[((51+p3)<<6)+ql];
      u64 best = k0; int bw = 0;
      if (k1 > best){ best = k1; bw = 1; }
      if (k2 > best){ best = k2; bw = 2; }
      if (k3 > best){ best = k3; bw = 3; }
      p0 += (bw==0); p1 += (bw==1); p2 += (bw==2); p3 += (bw==3);
      if (r > 0){   // drop the single farthest (rank 0), keep ranks 1..16
        const int j = 4095 - (int)((u32)best);
        const float4 nb = P[j];
        const float rx = nb.x - qp.x;
        const float ry = nb.y - qp.y;
        const float rz = nb.z - qp.z;
        ro[(r-1)*3+0] = rx; ro[(r-1)*3+1] = ry; ro[(r-1)*3+2] = rz;
        sm0 += rx; sm1 += ry; sm2 += rz;
        sm3 += rx*rx; sm4 += rx*ry; sm5 += rx*rz;
        sm6 += ry*ry; sm7 += ry*rz; sm8 += rz*rz;
      }
    }
  }
  #pragma unroll
  for (int off=1; off<16; off<<=1){
    sm0 += __shfl_xor(sm0, off); sm1 += __shfl_xor(sm1, off); sm2 += __shfl_xor(sm2, off);
    sm3 += __shfl_xor(sm3, off); sm4 += __shfl_xor(sm4, off); sm5 += __shfl_xor(sm5, off);
    sm6 += __shfl_xor(sm6, off); sm7 += __shfl_xor(sm7, off); sm8 += __shfl_xor(sm8, off);
  }
  if (lane == 0){
    atomicAdd(&mom[0], sm0); atomicAdd(&mom[1], sm1); atomicAdd(&mom[2], sm2);
    atomicAdd(&mom[3], sm3); atomicAdd(&mom[4], sm4); atomicAdd(&mom[5], sm5);
    atomicAdd(&mom[6], sm6); atomicAdd(&mom[7], sm7); atomicAdd(&mom[8], sm8);
  }
}

// BN1 stats analytically from rel moments: mean1 = w1*E[r]+b1, var1 = w1^T Cov(r) w1.
__global__ void stats1_kernel(const float* __restrict__ mom,
                              const float* __restrict__ w1, const float* __restrict__ b1,
                              const float* __restrict__ gamma, const float* __restrict__ beta,
                              float* __restrict__ s1, float* __restrict__ t1){
  const int o = threadIdx.x;           // 64 threads
  const float Minv = 1.0f / 524288.0f;
  float m0 = mom[0]*Minv, m1 = mom[1]*Minv, m2 = mom[2]*Minv;
  float cxx = mom[3]*Minv - m0*m0;
  float cxy = mom[4]*Minv - m0*m1;
  float cxz = mom[5]*Minv - m0*m2;
  float cyy = mom[6]*Minv - m1*m1;
  float cyz = mom[7]*Minv - m1*m2;
  float czz = mom[8]*Minv - m2*m2;
  float wx = w1[o*3+0], wy = w1[o*3+1], wz = w1[o*3+2];
  float mu  = wx*m0 + wy*m1 + wz*m2 + b1[o];
  float var = wx*wx*cxx + wy*wy*cyy + wz*wz*czz
            + 2.0f*(wx*wy*cxy + wx*wz*cxz + wy*wz*cyz);
  float istd = rsqrtf(var + 1e-5f);
  float g = gamma[o];
  s1[o] = g*istd;
  t1[o] = beta[o] - mu*g*istd;
}

// Pass 2: recompute h1, g2 = w2@h1+b2, accumulate per-channel sum/sumsq (BN2 stats).
__global__ __launch_bounds__(256) void pass2_kernel(const float* __restrict__ rel,
     const float* __restrict__ w1, const float* __restrict__ b1,
     const float* __restrict__ s1, const float* __restrict__ t1,
     const float* __restrict__ w2, const float* __restrict__ b2,
     float* __restrict__ gsum, float* __restrict__ gsq){
  __shared__ float lsum[64], lsq[64];
  const int tid = threadIdx.x;
  const int lane = tid & 63;
  if (tid < 64){ lsum[tid] = 0.0f; lsq[tid] = 0.0f; }
  __syncthreads();
  const size_t e = (size_t)blockIdx.x*256 + tid;
  const float rx = rel[e*3+0], ry = rel[e*3+1], rz = rel[e*3+2];
  float h1[64];
  #pragma unroll
  for (int o=0;o<64;o++){
    float g = fmaf(w1[o*3+0], rx, fmaf(w1[o*3+1], ry, fmaf(w1[o*3+2], rz, b1[o])));
    h1[o] = fmaxf(fmaf(g, s1[o], t1[o]), 0.0f);
  }
  for (int o=0;o<64;o++){
    const float* __restrict__ row = w2 + o*64;
    float a0=0,a1=0,a2=0,a3=0;
    #pragma unroll
    for (int c=0;c<64;c+=4){
      a0 = fmaf(row[c+0], h1[c+0], a0);
      a1 = fmaf(row[c+1], h1[c+1], a1);
      a2 = fmaf(row[c+2], h1[c+2], a2);
      a3 = fmaf(row[c+3], h1[c+3], a3);
    }
    float g2 = ((a0+a1)+(a2+a3)) + b2[o];
    float q2 = g2*g2;
    #pragma unroll
    for (int off=32; off>0; off>>=1){
      g2 += __shfl_down(g2, off);
      q2 += __shfl_down(q2, off);
    }
    if (lane == 0){ atomicAdd(&lsum[o], g2); atomicAdd(&lsq[o], q2); }
  }
  __syncthreads();
  if (tid < 64){ atomicAdd(&gsum[tid], lsum[tid]); atomicAdd(&gsq[tid], lsq[tid]); }
}

__global__ void stats2_kernel(const float* __restrict__ gsum, const float* __restrict__ gsq,
                              const float* __restrict__ gamma, const float* __restrict__ beta,
                              float* __restrict__ s2, float* __restrict__ t2){
  const int o = threadIdx.x;
  const float Minv = 1.0f / 524288.0f;
  float mu  = gsum[o]*Minv;
  float var = gsq[o]*Minv - mu*mu;
  float istd = rsqrtf(var + 1e-5f);
  float g = gamma[o];
  s2[o] = g*istd;
  t2[o] = beta[o] - mu*g*istd;
}

// Pass 3: h1 -> h2 -> g3, max over k (lanes grouped 16 per point), write out[b][o][n].
__global__ __launch_bounds__(256) void pass3_kernel(const float* __restrict__ rel,
     const float* __restrict__ w1, const float* __restrict__ b1,
     const float* __restrict__ s1, const float* __restrict__ t1,
     const float* __restrict__ w2, const float* __restrict__ b2,
     const float* __restrict__ s2, const float* __restrict__ t2,
     float* __restrict__ out){
  const int tid  = threadIdx.x;
  const int lane = tid & 63;
  const size_t e = (size_t)blockIdx.x*256 + tid;
  const int b = (int)(e >> 16);
  const int n = (int)((e >> 4) & 4095);
  const float rx = rel[e*3+0], ry = rel[e*3+1], rz = rel[e*3+2];
  float h1[64];
  #pragma unroll
  for (int o=0;o<64;o++){
    float g = fmaf(w1[o*3+0], rx, fmaf(w1[o*3+1], ry, fmaf(w1[o*3+2], rz, b1[o])));
    h1[o] = fmaxf(fmaf(g, s1[o], t1[o]), 0.0f);
  }
  float h2[64];
  for (int o=0;o<64;o++){
    const float* __restrict__ row = w2 + o*64;
    float a0=0,a1=0,a2=0,a3=0;
    #pragma unroll
    for (int c=0;c<64;c+=4){
      a0 = fmaf(row[c+0], h1[c+0], a0);
      a1 = fmaf(row[c+1], h1[c+1], a1);
      a2 = fmaf(row[c+2], h1[c+2], a2);
      a3 = fmaf(row[c+3], h1[c+3], a3);
    }
    float g2 = ((a0+a1)+(a2+a3)) + b2[o];
    h2[o] = fmaxf(fmaf(g2, s2[o], t2[o]), 0.0f);
  }
  for (int o=0;o<64;o++){
    const float* __restrict__ row = w2 + o*64;
    float a0=0,a1=0,a2=0,a3=0;
    #pragma unroll
    for (int c=0;c<64;c+=4){
      a0 = fmaf(row[c+0], h2[c+0], a0);
      a1 = fmaf(row[c+1], h2[c+1], a1);
      a2 = fmaf(row[c+2], h2[c+2], a2);
      a3 = fmaf(row[c+3], h2[c+3], a3);
    }
    float g3 = ((a0+a1)+(a2+a3)) + b2[o];
    g3 = fmaxf(g3, __shfl_xor(g3, 1));
    g3 = fmaxf(g3, __shfl_xor(g3, 2));
    g3 = fmaxf(g3, __shfl_xor(g3, 4));
    g3 = fmaxf(g3, __shfl_xor(g3, 8));
    if ((lane & 15) == 0){
      out[(((size_t)b*64 + o) << 12) + n] = g3;
    }
  }
}

extern "C" void kernel_launch(void* const* d_in, const int* in_sizes, int n_in,
                              void* d_out, int out_size, void* d_ws, size_t ws_size,
                              hipStream_t stream){
  const float* xyz   = (const float*)d_in[0];
  const float* w1    = (const float*)d_in[1];
  const float* b1    = (const float*)d_in[2];
  const float* w2    = (const float*)d_in[3];
  const float* b2    = (const float*)d_in[4];
  const float* gamma = (const float*)d_in[5];
  const float* beta  = (const float*)d_in[6];
  float* out = (float*)d_out;
  float* ws  = (float*)d_ws;

  float*  rel  = ws + REL_OFF;
  float4* pts4 = (float4*)(ws + PTS4_OFF);
  float*  mom  = ws + ACC_OFF;        // 9 used (padded to 16)
  float*  gsum = mom + 16;            // 64
  float*  gsq  = mom + 80;            // 64
  float*  s1   = ws + 1704080;
  float*  t1   = ws + 1704144;
  float*  s2   = ws + 1704208;
  float*  t2   = ws + 1704272;

  hipMemsetAsync(mom, 0, 144*sizeof(float), stream);
  prep_kernel  <<<128,  256, 0, stream>>>(xyz, pts4);
  knn_kernel   <<<512,  256, 0, stream>>>(pts4, rel, mom);
  stats1_kernel<<<1,     64, 0, stream>>>(mom, w1, b1, gamma, beta, s1, t1);
  pass2_kernel <<<2048, 256, 0, stream>>>(rel, w1, b1, s1, t1, w2, b2, gsum, gsq);
  stats2_kernel<<<1,     64, 0, stream>>>(gsum, gsq, gamma, beta, s2, t2);
  pass3_kernel <<<2048, 256, 0, stream>>>(rel, w1, b1, s1, t1, w2, b2, s2, t2, out);
}